// Round 3
// baseline (288.212 us; speedup 1.0000x reference)
//
#include <hip/hip_runtime.h>
#include <hip/hip_bf16.h>

// Weighted BP decoder, (3,6)-regular Tanner graph.
// Check r owns edges 6r..6r+5 (row-major nonzeros of H) -> check-side extrinsic
// products are in-register prefix/suffix products (c_prod_idx unused).
//
// Messages in log2 domain: d = c2v/ln2. With z = exp2(a), t = tanh(a*ln2/2)
// = (z-1)/(z+1); extrinsic product p = A/B with A = prod(z-1), B = prod(z+1)
// (all-but-one). Then
//   d_new = log2(B + kappa*A) - log2(B - kappa*A)
// -> per edge-row transcendentals: exp2 + 2*log2 (no rcp; tanh never formed).
// Exponent clamped at 24 (== clamping z at 2^24): products stay <= 2^120 and
// B >= |A| keeps both log args >= (1-kappa)*B > 0.
//
// R3 restructure: 256-thread blocks, 2 checks/thread, 2 batch rows (v2f).
//  - barriers are 4 waves wide (was 8) and up to 5 independent blocks fit per
//    CU (LDS 28.7KB) -> much better issue-slot fill during barrier/LDS waits
//  - 2 independent check-chains per thread = 2x ILP across the transc chain
//  - check1 weights + lit gathers issued after barrier #1 so their latency
//    hides behind check0's compute; keeps peak live VGPRs < 128.

namespace {

typedef float v2f __attribute__((ext_vector_type(2)));

constexpr int T      = 256;   // threads/block; each owns checks tid and tid+256
constexpr int MCHK   = 512;
constexpr int NVAR   = 1024;
constexpr int EEDG   = 3072;
constexpr int NITER  = 10;
constexpr int STRIDE = 7;     // v2f slots per check (6 + 1 pad)
constexpr int BATCH  = 8192;
constexpr int NOUT   = 512;   // N - M outputs per row

constexpr float LOG2E = 1.4426950408889634f;
constexpr float LN2   = 0.6931471805599453f;
constexpr float KAPPA = 0.999995f;
constexpr float ACLMP = 24.0f;   // exp2 arg clamp == z <= 2^24

__device__ __forceinline__ float fast_exp2(float x) { return __builtin_amdgcn_exp2f(x); }
__device__ __forceinline__ float fast_log2(float x) { return __builtin_amdgcn_logf(x); }
__device__ __forceinline__ float fast_rcp (float x) { return __builtin_amdgcn_rcpf(x); }

__device__ __forceinline__ void check_update(const v2f* __restrict__ g,
                                             const float* __restrict__ w,
                                             const v2f* __restrict__ Lli,
                                             v2f* __restrict__ d)
{
    v2f zm[6], zp[6];
    #pragma unroll
    for (int j = 0; j < 6; ++j) {
        v2f a = w[2*j] * g[2*j] + w[2*j+1] * g[2*j+1] + Lli[j];   // pk fma
        a = __builtin_elementwise_min(a, (v2f)(ACLMP));           // pk min
        v2f z;
        z.x = fast_exp2(a.x);
        z.y = fast_exp2(a.y);
        zm[j] = z - 1.f;
        zp[j] = z + 1.f;
    }
    v2f A[6], B[6];
    {
        v2f P1=zm[0], P2=P1*zm[1], P3=P2*zm[2], P4=P3*zm[3], P5=P4*zm[4];
        v2f S4=zm[5], S3=S4*zm[4], S2=S3*zm[3], S1=S2*zm[2], S0=S1*zm[1];
        A[0]=S0; A[1]=P1*S1; A[2]=P2*S2; A[3]=P3*S3; A[4]=P4*S4; A[5]=P5;
    }
    {
        v2f P1=zp[0], P2=P1*zp[1], P3=P2*zp[2], P4=P3*zp[3], P5=P4*zp[4];
        v2f S4=zp[5], S3=S4*zp[4], S2=S3*zp[3], S1=S2*zp[2], S0=S1*zp[1];
        B[0]=S0; B[1]=P1*S1; B[2]=P2*S2; B[3]=P3*S3; B[4]=P4*S4; B[5]=P5;
    }
    #pragma unroll
    for (int j = 0; j < 6; ++j) {
        v2f num = KAPPA * A[j] + B[j];    // pk fma
        v2f den = B[j] - KAPPA * A[j];    // pk fma
        v2f dd;
        dd.x = fast_log2(num.x) - fast_log2(num.x == num.x ? den.x : den.x); // keep simple:
        dd.x = fast_log2(num.x) - fast_log2(den.x);
        dd.y = fast_log2(num.y) - fast_log2(den.y);
        d[j] = dd;
    }
}

__global__ __launch_bounds__(T, 4)
void bp_decode(const float* __restrict__ llr,
               const float* __restrict__ w_iter,
               const float* __restrict__ llr_iter,
               const float* __restrict__ w_final,
               const float* __restrict__ llr_final,
               const int*  __restrict__ v_sum_idx,
               const int*  __restrict__ edge_var,
               const int*  __restrict__ final_idx,
               float* __restrict__ out)
{
    __shared__ v2f Ad[MCHK * STRIDE];   // 28672 B

    const int  tid = threadIdx.x;
    const long b0  = (long)blockIdx.x * 2;

    // ---- init: d = 0 (14 slots per thread covers all 3584) ----
    #pragma unroll
    for (int k = 0; k < 2 * STRIDE; ++k)
        Ad[k * T + tid] = (v2f)(0.f);

    // ---- static per-thread graph data for checks c0=tid, c1=tid+256 ----
    unsigned goffp[12];   // padded LDS slots of the 24 neighbor edges, 2x16b packed
    unsigned varp[6];     // the 12 variable ids, 2x16b packed
    v2f      Lpre[12];    // llr (both rows) * LOG2E per edge

    #pragma unroll
    for (int cc = 0; cc < 2; ++cc) {
        const int c = tid + cc * T;
        int nb[12];
        {
            const int4* p = (const int4*)(v_sum_idx + 12 * c);
            int4 q0 = p[0], q1 = p[1], q2 = p[2];
            nb[0]=q0.x; nb[1]=q0.y; nb[2]=q0.z; nb[3]=q0.w;
            nb[4]=q1.x; nb[5]=q1.y; nb[6]=q1.z; nb[7]=q1.w;
            nb[8]=q2.x; nb[9]=q2.y; nb[10]=q2.z; nb[11]=q2.w;
        }
        #pragma unroll
        for (int i = 0; i < 6; ++i) {
            unsigned s0 = (unsigned)((nb[2*i]   / 6) * STRIDE + (nb[2*i]   % 6));
            unsigned s1 = (unsigned)((nb[2*i+1] / 6) * STRIDE + (nb[2*i+1] % 6));
            goffp[6*cc + i] = s0 | (s1 << 16);
        }
        int var[6];
        {
            const int2* p = (const int2*)(edge_var + 6 * c);
            int2 q0 = p[0], q1 = p[1], q2 = p[2];
            var[0]=q0.x; var[1]=q0.y; var[2]=q1.x; var[3]=q1.y; var[4]=q2.x; var[5]=q2.y;
        }
        #pragma unroll
        for (int i = 0; i < 3; ++i)
            varp[3*cc + i] = (unsigned)var[2*i] | ((unsigned)var[2*i+1] << 16);
        #pragma unroll
        for (int j = 0; j < 6; ++j) {
            v2f L;
            L.x = llr[ b0      * NVAR + var[j]];
            L.y = llr[(b0 + 1) * NVAR + var[j]];
            Lpre[6*cc + j] = L * LOG2E;
        }
    }

    const int own0 = STRIDE * tid;
    const int own1 = STRIDE * (tid + T);

    __syncthreads();

    #pragma unroll 1
    for (int it = 0; it < NITER; ++it) {
        const float* wit = w_iter + it * (EEDG * 2);

        // check0 weights issued before the LDS gathers (latency overlaps them)
        float w0[12];
        {
            const float* p = wit + 12 * tid;
            float4 a = ((const float4*)p)[0], b = ((const float4*)p)[1], c = ((const float4*)p)[2];
            w0[0]=a.x; w0[1]=a.y; w0[2]=a.z; w0[3]=a.w;
            w0[4]=b.x; w0[5]=b.y; w0[6]=b.z; w0[7]=b.w;
            w0[8]=c.x; w0[9]=c.y; w0[10]=c.z; w0[11]=c.w;
        }

        // gather all 24 extrinsic messages (ds_read_b64)
        v2f g0[12], g1[12];
        #pragma unroll
        for (int i = 0; i < 6; ++i) {
            unsigned p = goffp[i];
            g0[2*i]   = Ad[p & 0xffffu];
            g0[2*i+1] = Ad[p >> 16];
        }
        #pragma unroll
        for (int i = 0; i < 6; ++i) {
            unsigned p = goffp[6 + i];
            g1[2*i]   = Ad[p & 0xffffu];
            g1[2*i+1] = Ad[p >> 16];
        }

        __syncthreads();   // all gathers landed before anyone overwrites in place

        // check1 weights + lit gathers land while check0 computes
        float w1[12];
        {
            const float* p = wit + 12 * tid + 6 * T * 2;   // edges of check tid+256
            float4 a = ((const float4*)p)[0], b = ((const float4*)p)[1], c = ((const float4*)p)[2];
            w1[0]=a.x; w1[1]=a.y; w1[2]=a.z; w1[3]=a.w;
            w1[4]=b.x; w1[5]=b.y; w1[6]=b.z; w1[7]=b.w;
            w1[8]=c.x; w1[9]=c.y; w1[10]=c.z; w1[11]=c.w;
        }
        const float* lit = llr_iter + it * NVAR;

        float lv0[6], lv1[6];
        #pragma unroll
        for (int i = 0; i < 3; ++i) {
            unsigned p = varp[i];
            lv0[2*i]   = lit[p & 0xffffu];
            lv0[2*i+1] = lit[p >> 16];
        }
        #pragma unroll
        for (int i = 0; i < 3; ++i) {
            unsigned p = varp[3 + i];
            lv1[2*i]   = lit[p & 0xffffu];
            lv1[2*i+1] = lit[p >> 16];
        }

        v2f Lli[6], d[6];
        #pragma unroll
        for (int j = 0; j < 6; ++j) Lli[j] = Lpre[j] * lv0[j];
        check_update(g0, w0, Lli, d);
        #pragma unroll
        for (int j = 0; j < 6; ++j) Ad[own0 + j] = d[j];

        #pragma unroll
        for (int j = 0; j < 6; ++j) Lli[j] = Lpre[6 + j] * lv1[j];
        check_update(g1, w1, Lli, d);
        #pragma unroll
        for (int j = 0; j < 6; ++j) Ad[own1 + j] = d[j];

        __syncthreads();   // writes visible before next iteration's gathers
    }

    // ---- final marginalization: variables tid and tid+256 (the 512 outputs) ----
    #pragma unroll
    for (int cc = 0; cc < 2; ++cc) {
        const int v = tid + cc * T;
        int f0 = final_idx[3*v], f1 = final_idx[3*v + 1], f2 = final_idx[3*v + 2];
        v2f d0 = Ad[(f0 / 6) * STRIDE + (f0 % 6)];
        v2f d1 = Ad[(f1 / 6) * STRIDE + (f1 % 6)];
        v2f d2 = Ad[(f2 / 6) * STRIDE + (f2 % 6)];
        float wf0 = w_final[3*v], wf1 = w_final[3*v + 1], wf2 = w_final[3*v + 2];
        float lf  = llr_final[v];
        float l0  = llr[ b0      * NVAR + v];
        float l1  = llr[(b0 + 1) * NVAR + v];

        float finx = (d0.x*wf0 + d1.x*wf1 + d2.x*wf2) * LN2;   // c2v = ln2 * d
        float finy = (d0.y*wf0 + d1.y*wf1 + d2.y*wf2) * LN2;
        float vx = fmaf(l0, lf, finx);
        float vy = fmaf(l1, lf, finy);
        out[ b0      * NOUT + v] = fast_rcp(1.f + fast_exp2(-vx * LOG2E));  // sigmoid
        out[(b0 + 1) * NOUT + v] = fast_rcp(1.f + fast_exp2(-vy * LOG2E));
    }
}

} // namespace

extern "C" void kernel_launch(void* const* d_in, const int* in_sizes, int n_in,
                              void* d_out, int out_size, void* d_ws, size_t ws_size,
                              hipStream_t stream)
{
    const float* llr       = (const float*)d_in[0];
    const float* w_iter    = (const float*)d_in[1];
    const float* llr_iter  = (const float*)d_in[2];
    const float* w_final   = (const float*)d_in[3];
    const float* llr_final = (const float*)d_in[4];
    const int*   v_sum_idx = (const int*)d_in[5];
    // d_in[6] = c_prod_idx: unused (check groups are consecutive by construction)
    const int*   edge_var  = (const int*)d_in[7];
    const int*   final_idx = (const int*)d_in[8];
    float* outp = (float*)d_out;

    dim3 grid(BATCH / 2), block(T);
    hipLaunchKernelGGL(bp_decode, grid, block, 0, stream,
                       llr, w_iter, llr_iter, w_final, llr_final,
                       v_sum_idx, edge_var, final_idx, outp);
}

// Round 4
// 241.727 us; speedup vs baseline: 1.1923x; 1.1923x over previous
//
#include <hip/hip_runtime.h>
#include <hip/hip_bf16.h>

// Weighted BP decoder, (3,6)-regular Tanner graph.
// Check r owns edges 6r..6r+5 (row-major nonzeros of H) -> check-side extrinsic
// products are in-register prefix/suffix products (c_prod_idx unused).
//
// Messages in log2 domain: d = c2v/ln2. With z = exp2(a), t = tanh(a*ln2/2)
// = (z-1)/(z+1); extrinsic product p = A/B with A = prod(z-1), B = prod(z+1)
// (all-but-one). Then
//   d_new = log2(B + kappa*A) - log2(B - kappa*A)
// -> per edge-row transcendentals: exp2 + 2*log2 (tanh/atanh never formed).
// Exponent clamped at 24 (== z <= 2^24): 5-way products <= 2^120, and
// B >= |A| keeps both log args >= (1-kappa)*B > 0.
//
// R4: 512 threads, 1 check/thread (R2's proven shape), FOUR batch rows per
// block on ext_vector_type(4) float (v_pk_* on f32 pairs):
//  - barriers per batch-row halved vs R2; weights/indices/loop amortized 2x
//  - 4 independent transc chains per thread hide exp2/log2 latency
//  - LDS gathers are folded into the accumulator immediately (a[6], 24 regs)
//    instead of holding g[12] (48 regs) -> peak live ~110 VGPR, NO SPILLS
//    (R3's failure mode: 58 MB scratch WRITE_SIZE from holding 2 checks' state)

namespace {

typedef float v4f __attribute__((ext_vector_type(4)));

constexpr int T      = 512;   // threads/block == checks
constexpr int ROWS   = 4;     // batch rows per block (v4f-packed)
constexpr int MCHK   = 512;
constexpr int NVAR   = 1024;
constexpr int NITER  = 10;
constexpr int STRIDE = 7;     // v4f slots per check (6 + 1 pad)
constexpr int BATCH  = 8192;
constexpr int NOUT   = 512;   // N - M outputs per row

constexpr float LOG2E = 1.4426950408889634f;
constexpr float LN2   = 0.6931471805599453f;
constexpr float KAPPA = 0.999995f;
constexpr float ACLMP = 24.0f;   // exp2 arg clamp == z <= 2^24

__device__ __forceinline__ float fast_exp2(float x) { return __builtin_amdgcn_exp2f(x); }
__device__ __forceinline__ float fast_log2(float x) { return __builtin_amdgcn_logf(x); }
__device__ __forceinline__ float fast_rcp (float x) { return __builtin_amdgcn_rcpf(x); }

__global__ __launch_bounds__(T, 2)
void bp_decode(const float* __restrict__ llr,
               const float* __restrict__ w_iter,
               const float* __restrict__ llr_iter,
               const float* __restrict__ w_final,
               const float* __restrict__ llr_final,
               const int*  __restrict__ v_sum_idx,
               const int*  __restrict__ edge_var,
               const int*  __restrict__ final_idx,
               float* __restrict__ out)
{
    __shared__ v4f Ad[MCHK * STRIDE];   // 57344 B, 4 rows packed per slot

    const int  tid = threadIdx.x;
    const long b0  = (long)blockIdx.x * ROWS;

    // ---- init: d = 0 ----
    #pragma unroll
    for (int k = 0; k < STRIDE; ++k)
        Ad[k * T + tid] = (v4f)(0.f);

    // ---- static per-thread graph data (my check = tid, edges 6*tid..6*tid+5) ----
    unsigned goffp[6];   // padded LDS slots of my 12 neighbor edges, 2x16b packed
    unsigned varp[3];    // my 6 variable ids, 2x16b packed
    v4f      Lpre[6];    // llr (4 rows) * LOG2E per edge
    {
        int nb[12];
        const int4* p = (const int4*)(v_sum_idx + 12 * tid);  // 48B-aligned
        int4 q0 = p[0], q1 = p[1], q2 = p[2];
        nb[0]=q0.x; nb[1]=q0.y; nb[2]=q0.z; nb[3]=q0.w;
        nb[4]=q1.x; nb[5]=q1.y; nb[6]=q1.z; nb[7]=q1.w;
        nb[8]=q2.x; nb[9]=q2.y; nb[10]=q2.z; nb[11]=q2.w;
        #pragma unroll
        for (int i = 0; i < 6; ++i) {
            unsigned s0 = (unsigned)((nb[2*i]   / 6) * STRIDE + (nb[2*i]   % 6));
            unsigned s1 = (unsigned)((nb[2*i+1] / 6) * STRIDE + (nb[2*i+1] % 6));
            goffp[i] = s0 | (s1 << 16);
        }
    }
    {
        int var[6];
        const int2* p = (const int2*)(edge_var + 6 * tid);    // 24B-aligned
        int2 q0 = p[0], q1 = p[1], q2 = p[2];
        var[0]=q0.x; var[1]=q0.y; var[2]=q1.x; var[3]=q1.y; var[4]=q2.x; var[5]=q2.y;
        #pragma unroll
        for (int i = 0; i < 3; ++i)
            varp[i] = (unsigned)var[2*i] | ((unsigned)var[2*i+1] << 16);
        #pragma unroll
        for (int j = 0; j < 6; ++j) {
            v4f L;
            L.x = llr[(b0 + 0) * NVAR + var[j]];
            L.y = llr[(b0 + 1) * NVAR + var[j]];
            L.z = llr[(b0 + 2) * NVAR + var[j]];
            L.w = llr[(b0 + 3) * NVAR + var[j]];
            Lpre[j] = L * LOG2E;
        }
    }

    const int own = STRIDE * tid;

    __syncthreads();

    #pragma unroll 1
    for (int it = 0; it < NITER; ++it) {
        // weights: my 6 edges x 2 = 12 consecutive floats (coalesced, L2-hot)
        float w[12];
        {
            const float* p = w_iter + it * 6144 + 12 * tid;
            float4 a = ((const float4*)p)[0], b = ((const float4*)p)[1], c = ((const float4*)p)[2];
            w[0]=a.x; w[1]=a.y; w[2]=a.z;  w[3]=a.w;
            w[4]=b.x; w[5]=b.y; w[6]=b.z;  w[7]=b.w;
            w[8]=c.x; w[9]=c.y; w[10]=c.z; w[11]=c.w;
        }
        // llr multipliers (4KB L1-hot table)
        const float* lit = llr_iter + it * NVAR;
        float lv[6];
        #pragma unroll
        for (int i = 0; i < 3; ++i) {
            unsigned p = varp[i];
            lv[2*i]   = lit[p & 0xffffu];
            lv[2*i+1] = lit[p >> 16];
        }

        // accumulators seeded with channel term; LDS gathers folded in
        // immediately (peak live: a[6]=24 regs, not g[12]=48 -> no spills)
        v4f a[6];
        #pragma unroll
        for (int j = 0; j < 6; ++j) a[j] = Lpre[j] * lv[j];
        #pragma unroll
        for (int i = 0; i < 6; ++i) {
            unsigned p  = goffp[i];
            v4f ga = Ad[p & 0xffffu];     // ds_read_b128
            v4f gb = Ad[p >> 16];
            a[i] = a[i] + w[2*i] * ga + w[2*i+1] * gb;   // pk fma
        }

        __syncthreads();   // all gathers landed before anyone overwrites in place

        // z-domain check update
        v4f zm[6], zp[6];
        #pragma unroll
        for (int j = 0; j < 6; ++j) {
            v4f aa = __builtin_elementwise_min(a[j], (v4f)(ACLMP));
            v4f z;
            z.x = fast_exp2(aa.x);
            z.y = fast_exp2(aa.y);
            z.z = fast_exp2(aa.z);
            z.w = fast_exp2(aa.w);
            zm[j] = z - 1.f;
            zp[j] = z + 1.f;
        }
        v4f A[6], B[6];
        {
            v4f P1=zm[0], P2=P1*zm[1], P3=P2*zm[2], P4=P3*zm[3], P5=P4*zm[4];
            v4f S4=zm[5], S3=S4*zm[4], S2=S3*zm[3], S1=S2*zm[2], S0=S1*zm[1];
            A[0]=S0; A[1]=P1*S1; A[2]=P2*S2; A[3]=P3*S3; A[4]=P4*S4; A[5]=P5;
        }
        {
            v4f P1=zp[0], P2=P1*zp[1], P3=P2*zp[2], P4=P3*zp[3], P5=P4*zp[4];
            v4f S4=zp[5], S3=S4*zp[4], S2=S3*zp[3], S1=S2*zp[2], S0=S1*zp[1];
            B[0]=S0; B[1]=P1*S1; B[2]=P2*S2; B[3]=P3*S3; B[4]=P4*S4; B[5]=P5;
        }
        #pragma unroll
        for (int j = 0; j < 6; ++j) {
            v4f num = KAPPA * A[j] + B[j];    // pk fma
            v4f den = B[j] - KAPPA * A[j];    // pk fma
            v4f d;
            d.x = fast_log2(num.x) - fast_log2(den.x);
            d.y = fast_log2(num.y) - fast_log2(den.y);
            d.z = fast_log2(num.z) - fast_log2(den.z);
            d.w = fast_log2(num.w) - fast_log2(den.w);
            Ad[own + j] = d;                  // ds_write_b128
        }

        __syncthreads();   // writes visible before next iteration's gathers
    }

    // ---- final marginalization: variable tid (the 512 output vars), 4 rows ----
    {
        int f0 = final_idx[3*tid], f1 = final_idx[3*tid + 1], f2 = final_idx[3*tid + 2];
        v4f d0 = Ad[(f0 / 6) * STRIDE + (f0 % 6)];
        v4f d1 = Ad[(f1 / 6) * STRIDE + (f1 % 6)];
        v4f d2 = Ad[(f2 / 6) * STRIDE + (f2 % 6)];
        float wf0 = w_final[3*tid], wf1 = w_final[3*tid + 1], wf2 = w_final[3*tid + 2];
        float lf  = llr_final[tid];
        v4f l;
        l.x = llr[(b0 + 0) * NVAR + tid];
        l.y = llr[(b0 + 1) * NVAR + tid];
        l.z = llr[(b0 + 2) * NVAR + tid];
        l.w = llr[(b0 + 3) * NVAR + tid];

        v4f fin = (d0 * wf0 + d1 * wf1 + d2 * wf2) * LN2;   // c2v = ln2 * d
        v4f v   = l * lf + fin;
        out[(b0 + 0) * NOUT + tid] = fast_rcp(1.f + fast_exp2(-v.x * LOG2E));
        out[(b0 + 1) * NOUT + tid] = fast_rcp(1.f + fast_exp2(-v.y * LOG2E));
        out[(b0 + 2) * NOUT + tid] = fast_rcp(1.f + fast_exp2(-v.z * LOG2E));
        out[(b0 + 3) * NOUT + tid] = fast_rcp(1.f + fast_exp2(-v.w * LOG2E));
    }
}

} // namespace

extern "C" void kernel_launch(void* const* d_in, const int* in_sizes, int n_in,
                              void* d_out, int out_size, void* d_ws, size_t ws_size,
                              hipStream_t stream)
{
    const float* llr       = (const float*)d_in[0];
    const float* w_iter    = (const float*)d_in[1];
    const float* llr_iter  = (const float*)d_in[2];
    const float* w_final   = (const float*)d_in[3];
    const float* llr_final = (const float*)d_in[4];
    const int*   v_sum_idx = (const int*)d_in[5];
    // d_in[6] = c_prod_idx: unused (check groups are consecutive by construction)
    const int*   edge_var  = (const int*)d_in[7];
    const int*   final_idx = (const int*)d_in[8];
    float* outp = (float*)d_out;

    dim3 grid(BATCH / ROWS), block(T);
    hipLaunchKernelGGL(bp_decode, grid, block, 0, stream,
                       llr, w_iter, llr_iter, w_final, llr_final,
                       v_sum_idx, edge_var, final_idx, outp);
}

// Round 5
// 211.316 us; speedup vs baseline: 1.3639x; 1.1439x over previous
//
#include <hip/hip_runtime.h>

// Weighted BP decoder, (3,6)-regular Tanner graph.
// Check r owns edges 6r..6r+5 (row-major nonzeros of H) -> check-side extrinsic
// products are in-register prefix/suffix products (c_prod_idx unused).
//
// Messages in log2 domain: d = c2v/ln2. With z = exp2(a), t = tanh(a*ln2/2)
// = (z-1)/(z+1); extrinsic product p = A/B with A = prod(z-1), B = prod(z+1)
// (all-but-one). Then
//   d_new = log2(B + kappa*A) - log2(B - kappa*A)
// -> per edge-row transcendentals: exp2 + 2*log2 (tanh/atanh never formed).
// Exponent clamped at 24 (== z <= 2^24): 5-way products <= 2^120, and
// B >= |A| keeps both log args >= (1-kappa)*B > 0.
//
// R5: R4 (512 thr, 1 check/thr, 4 batch rows on v4f) with two fixes:
//  - STRIDE 7 -> 6: LDS 57.3 KB -> 49152 B. R4's occupancy collapse (22%,
//    1 block/CU) showed the co-residency LDS pool is ~96-112 KB, not 160 KB;
//    at 48 KB two blocks co-reside again -> barrier stalls covered by the
//    other block. Stride 6 also makes LDS slot == edge index (no div/mod).
//    Own-slot writes become 2-way bank-aliased (lanes t, t+4), which is free.
//  - software pipeline: next iteration's weights + llr_iter values prefetched
//    right after barrier #1, latency hidden under the transcendental phase.

namespace {

typedef float v4f __attribute__((ext_vector_type(4)));

constexpr int T      = 512;   // threads/block == checks
constexpr int ROWS   = 4;     // batch rows per block (v4f-packed)
constexpr int EEDG   = 3072;
constexpr int NVAR   = 1024;
constexpr int NITER  = 10;
constexpr int BATCH  = 8192;
constexpr int NOUT   = 512;   // N - M outputs per row

constexpr float LOG2E = 1.4426950408889634f;
constexpr float LN2   = 0.6931471805599453f;
constexpr float KAPPA = 0.999995f;
constexpr float ACLMP = 24.0f;   // exp2 arg clamp == z <= 2^24

__device__ __forceinline__ float fast_exp2(float x) { return __builtin_amdgcn_exp2f(x); }
__device__ __forceinline__ float fast_log2(float x) { return __builtin_amdgcn_logf(x); }
__device__ __forceinline__ float fast_rcp (float x) { return __builtin_amdgcn_rcpf(x); }

__global__ __launch_bounds__(T, 2)
void bp_decode(const float* __restrict__ llr,
               const float* __restrict__ w_iter,
               const float* __restrict__ llr_iter,
               const float* __restrict__ w_final,
               const float* __restrict__ llr_final,
               const int*  __restrict__ v_sum_idx,
               const int*  __restrict__ edge_var,
               const int*  __restrict__ final_idx,
               float* __restrict__ out)
{
    __shared__ v4f Ad[EEDG];   // 49152 B; slot of edge e is simply e

    const int  tid = threadIdx.x;
    const long b0  = (long)blockIdx.x * ROWS;

    // ---- init: d = 0 ----
    #pragma unroll
    for (int k = 0; k < 6; ++k)
        Ad[k * T + tid] = (v4f)(0.f);

    // ---- static per-thread graph data (my check = tid, edges 6*tid..6*tid+5) ----
    unsigned nbp[6];    // my 12 neighbor-edge indices (== LDS slots), 2x16b packed
    unsigned varp[3];   // my 6 variable ids, 2x16b packed
    v4f      Lpre[6];   // llr (4 rows) * LOG2E per edge
    {
        const int4* p = (const int4*)(v_sum_idx + 12 * tid);  // 48B-aligned
        int4 q0 = p[0], q1 = p[1], q2 = p[2];
        nbp[0] = (unsigned)q0.x | ((unsigned)q0.y << 16);
        nbp[1] = (unsigned)q0.z | ((unsigned)q0.w << 16);
        nbp[2] = (unsigned)q1.x | ((unsigned)q1.y << 16);
        nbp[3] = (unsigned)q1.z | ((unsigned)q1.w << 16);
        nbp[4] = (unsigned)q2.x | ((unsigned)q2.y << 16);
        nbp[5] = (unsigned)q2.z | ((unsigned)q2.w << 16);
    }
    {
        int var[6];
        const int2* p = (const int2*)(edge_var + 6 * tid);    // 24B-aligned
        int2 q0 = p[0], q1 = p[1], q2 = p[2];
        var[0]=q0.x; var[1]=q0.y; var[2]=q1.x; var[3]=q1.y; var[4]=q2.x; var[5]=q2.y;
        #pragma unroll
        for (int i = 0; i < 3; ++i)
            varp[i] = (unsigned)var[2*i] | ((unsigned)var[2*i+1] << 16);
        #pragma unroll
        for (int j = 0; j < 6; ++j) {
            v4f L;
            L.x = llr[(b0 + 0) * NVAR + var[j]];
            L.y = llr[(b0 + 1) * NVAR + var[j]];
            L.z = llr[(b0 + 2) * NVAR + var[j]];
            L.w = llr[(b0 + 3) * NVAR + var[j]];
            Lpre[j] = L * LOG2E;
        }
    }

    const int own = 6 * tid;

    // prefetch iteration 0 uniforms
    float w[12], lv[6];
    {
        const float* p = w_iter + 12 * tid;
        float4 a = ((const float4*)p)[0], b = ((const float4*)p)[1], c = ((const float4*)p)[2];
        w[0]=a.x; w[1]=a.y; w[2]=a.z;  w[3]=a.w;
        w[4]=b.x; w[5]=b.y; w[6]=b.z;  w[7]=b.w;
        w[8]=c.x; w[9]=c.y; w[10]=c.z; w[11]=c.w;
        #pragma unroll
        for (int i = 0; i < 3; ++i) {
            unsigned q = varp[i];
            lv[2*i]   = llr_iter[q & 0xffffu];
            lv[2*i+1] = llr_iter[q >> 16];
        }
    }

    __syncthreads();

    #pragma unroll 2
    for (int it = 0; it < NITER; ++it) {
        // accumulators seeded with channel term; LDS gathers folded in
        // immediately (peak live small -> no spills)
        v4f a[6];
        #pragma unroll
        for (int j = 0; j < 6; ++j) a[j] = Lpre[j] * lv[j];
        #pragma unroll
        for (int i = 0; i < 6; ++i) {
            unsigned p  = nbp[i];
            v4f ga = Ad[p & 0xffffu];     // ds_read_b128
            v4f gb = Ad[p >> 16];
            a[i] = a[i] + w[2*i] * ga + w[2*i+1] * gb;   // pk fma
        }

        __syncthreads();   // all gathers landed before anyone overwrites in place

        // prefetch next iteration's uniforms; latency hides under transc phase
        {
            const int itn = (it + 1 < NITER) ? it + 1 : it;   // clamp, no OOB
            const float* p = w_iter + itn * (EEDG * 2) + 12 * tid;
            float4 qa = ((const float4*)p)[0], qb = ((const float4*)p)[1], qc = ((const float4*)p)[2];
            const float* lit = llr_iter + itn * NVAR;
            float lvn[6];
            #pragma unroll
            for (int i = 0; i < 3; ++i) {
                unsigned q = varp[i];
                lvn[2*i]   = lit[q & 0xffffu];
                lvn[2*i+1] = lit[q >> 16];
            }

            // z-domain check update (uses current w, lv via a[])
            v4f zm[6], zp[6];
            #pragma unroll
            for (int j = 0; j < 6; ++j) {
                v4f aa = __builtin_elementwise_min(a[j], (v4f)(ACLMP));
                v4f z;
                z.x = fast_exp2(aa.x);
                z.y = fast_exp2(aa.y);
                z.z = fast_exp2(aa.z);
                z.w = fast_exp2(aa.w);
                zm[j] = z - 1.f;
                zp[j] = z + 1.f;
            }
            v4f A[6], B[6];
            {
                v4f P1=zm[0], P2=P1*zm[1], P3=P2*zm[2], P4=P3*zm[3], P5=P4*zm[4];
                v4f S4=zm[5], S3=S4*zm[4], S2=S3*zm[3], S1=S2*zm[2], S0=S1*zm[1];
                A[0]=S0; A[1]=P1*S1; A[2]=P2*S2; A[3]=P3*S3; A[4]=P4*S4; A[5]=P5;
            }
            {
                v4f P1=zp[0], P2=P1*zp[1], P3=P2*zp[2], P4=P3*zp[3], P5=P4*zp[4];
                v4f S4=zp[5], S3=S4*zp[4], S2=S3*zp[3], S1=S2*zp[2], S0=S1*zp[1];
                B[0]=S0; B[1]=P1*S1; B[2]=P2*S2; B[3]=P3*S3; B[4]=P4*S4; B[5]=P5;
            }
            #pragma unroll
            for (int j = 0; j < 6; ++j) {
                v4f num = KAPPA * A[j] + B[j];    // pk fma
                v4f den = B[j] - KAPPA * A[j];    // pk fma
                v4f d;
                d.x = fast_log2(num.x) - fast_log2(den.x);
                d.y = fast_log2(num.y) - fast_log2(den.y);
                d.z = fast_log2(num.z) - fast_log2(den.z);
                d.w = fast_log2(num.w) - fast_log2(den.w);
                Ad[own + j] = d;                  // ds_write_b128
            }

            // rotate prefetched uniforms into place (unroll-2 elides the movs)
            w[0]=qa.x; w[1]=qa.y; w[2]=qa.z;  w[3]=qa.w;
            w[4]=qb.x; w[5]=qb.y; w[6]=qb.z;  w[7]=qb.w;
            w[8]=qc.x; w[9]=qc.y; w[10]=qc.z; w[11]=qc.w;
            #pragma unroll
            for (int j = 0; j < 6; ++j) lv[j] = lvn[j];
        }

        __syncthreads();   // writes visible before next iteration's gathers
    }

    // ---- final marginalization: variable tid (the 512 output vars), 4 rows ----
    {
        int f0 = final_idx[3*tid], f1 = final_idx[3*tid + 1], f2 = final_idx[3*tid + 2];
        v4f d0 = Ad[f0];
        v4f d1 = Ad[f1];
        v4f d2 = Ad[f2];
        float wf0 = w_final[3*tid], wf1 = w_final[3*tid + 1], wf2 = w_final[3*tid + 2];
        float lf  = llr_final[tid];
        v4f l;
        l.x = llr[(b0 + 0) * NVAR + tid];
        l.y = llr[(b0 + 1) * NVAR + tid];
        l.z = llr[(b0 + 2) * NVAR + tid];
        l.w = llr[(b0 + 3) * NVAR + tid];

        v4f fin = (d0 * wf0 + d1 * wf1 + d2 * wf2) * LN2;   // c2v = ln2 * d
        v4f v   = l * lf + fin;
        out[(b0 + 0) * NOUT + tid] = fast_rcp(1.f + fast_exp2(-v.x * LOG2E));
        out[(b0 + 1) * NOUT + tid] = fast_rcp(1.f + fast_exp2(-v.y * LOG2E));
        out[(b0 + 2) * NOUT + tid] = fast_rcp(1.f + fast_exp2(-v.z * LOG2E));
        out[(b0 + 3) * NOUT + tid] = fast_rcp(1.f + fast_exp2(-v.w * LOG2E));
    }
}

} // namespace

extern "C" void kernel_launch(void* const* d_in, const int* in_sizes, int n_in,
                              void* d_out, int out_size, void* d_ws, size_t ws_size,
                              hipStream_t stream)
{
    const float* llr       = (const float*)d_in[0];
    const float* w_iter    = (const float*)d_in[1];
    const float* llr_iter  = (const float*)d_in[2];
    const float* w_final   = (const float*)d_in[3];
    const float* llr_final = (const float*)d_in[4];
    const int*   v_sum_idx = (const int*)d_in[5];
    // d_in[6] = c_prod_idx: unused (check groups are consecutive by construction)
    const int*   edge_var  = (const int*)d_in[7];
    const int*   final_idx = (const int*)d_in[8];
    float* outp = (float*)d_out;

    dim3 grid(BATCH / ROWS), block(T);
    hipLaunchKernelGGL(bp_decode, grid, block, 0, stream,
                       llr, w_iter, llr_iter, w_final, llr_final,
                       v_sum_idx, edge_var, final_idx, outp);
}